// Round 14
// baseline (461.679 us; speedup 1.0000x reference)
//
#include <hip/hip_runtime.h>
#include <hip/hip_bf16.h>

typedef __hip_bfloat16 bf16;

#define BATCH 128
#define SEQ   200
#define NUMQ  1000
#define DD    64
#define MM    50
#define MG    10     // m-rows per wave
#define NMG   5      // m-groups
#define CHUNKS 10    // K2s waves / 20-step chunks
#define CLEN   20
#define CR     20    // replay chunks
#define CRL    10    // replay chunk length

// Proven rounds 5-13: floats f32, ints int32, ws >= 51MB.
// PMC lessons: dword stores -> TCC RFO (round 12); width/occupancy alone don't fix
// K2's ~2.7TB/s write rate (rounds 10/11/13). This round: fill-shaped contiguous slabs.

__device__ __forceinline__ float rdlane(float v, int j) {
    return __uint_as_float(__builtin_amdgcn_readlane(__float_as_uint(v), j));
}

// ---------------- K1: wide parallel precompute of w (softmax), e, a ----------------
__global__ __launch_bounds__(256) void k1_precompute(
    const int* __restrict__ q, const int* __restrict__ r,
    const float* __restrict__ k_emb, const float* __restrict__ v_emb,
    const float* __restrict__ Mk,
    const float* __restrict__ We, const float* __restrict__ be,
    const float* __restrict__ Wa, const float* __restrict__ ba,
    float* __restrict__ w_buf, float* __restrict__ e_buf, float* __restrict__ a_buf)
{
    __shared__ float Mk_l[MM][DD + 1];
    __shared__ float kv_l[4][128];

    const int tid = threadIdx.x;
    for (int i = tid; i < MM * DD; i += 256)
        Mk_l[i >> 6][i & 63] = Mk[i];

    const int w    = tid >> 6;
    const int lane = tid & 63;
    const int row  = blockIdx.x * 4 + w;

    int qi = q[row], ri = r[row];
    qi = min(max(qi, 0), NUMQ - 1);
    ri = min(max(ri, 0), 1);
    const int xi = qi + ri * NUMQ;

    kv_l[w][lane]      = k_emb[(size_t)qi * DD + lane];
    kv_l[w][64 + lane] = v_emb[(size_t)xi * DD + lane];
    __syncthreads();

    float s = 0.f;
    if (lane < MM) {
        #pragma unroll
        for (int dd = 0; dd < DD; ++dd)
            s += kv_l[w][dd] * Mk_l[lane][dd];
    }
    float mx = (lane < MM) ? s : -1e30f;
    #pragma unroll
    for (int off = 32; off >= 1; off >>= 1)
        mx = fmaxf(mx, __shfl_xor(mx, off, 64));
    float ex = (lane < MM) ? expf(s - mx) : 0.f;
    float sm = ex;
    #pragma unroll
    for (int off = 32; off >= 1; off >>= 1)
        sm += __shfl_xor(sm, off, 64);
    if (lane < MM)
        w_buf[(size_t)row * MM + lane] = ex / sm;

    float ea = be[lane], aa = ba[lane];
    #pragma unroll
    for (int dd = 0; dd < DD; ++dd) {
        const float vb = kv_l[w][64 + dd];
        ea = __builtin_fmaf(vb, We[dd * DD + lane], ea);
        aa = __builtin_fmaf(vb, Wa[dd * DD + lane], aa);
    }
    e_buf[(size_t)row * DD + lane] = 1.f / (1.f + expf(-ea));
    a_buf[(size_t)row * DD + lane] = tanhf(aa);
}

// ---------------- K2s: entry states at 10-step granularity, (b,c)-major layout ----------------
__global__ __launch_bounds__(640, 4) void k2s_states(
    const float* __restrict__ Mv0,
    const float* __restrict__ w_buf, const float* __restrict__ e_buf,
    const float* __restrict__ a_buf,
    float* __restrict__ states)
{
    __shared__ float S[MG][DD];

    const int blk  = blockIdx.x;
    const int b    = blk / NMG;
    const int mg   = blk % NMG;
    const int tid  = threadIdx.x;
    const int wv   = tid >> 6;
    const int lane = tid & 63;
    const int t0   = wv * CLEN;
    const int mb   = mg * MG;

    const float* wrow = w_buf + (size_t)b * SEQ * MM + mb;
    const float* erow = e_buf + (size_t)b * SEQ * DD;
    const float* arow = a_buf + (size_t)b * SEQ * DD;

    float A[MG], B[MG];
    #pragma unroll
    for (int j = 0; j < MG; ++j) { A[j] = 1.f; B[j] = 0.f; }

    float wreg = (lane < MG) ? wrow[(size_t)t0 * MM + lane] : 0.f;
    float e_n  = erow[(size_t)t0 * DD + lane];
    float a_n  = arow[(size_t)t0 * DD + lane];

    for (int tt = 0; tt < CLEN; ++tt) {
        const int t = t0 + tt;
        const float e_v = e_n, a_v = a_n, wcur = wreg;
        if (t + 1 < SEQ) {
            wreg = (lane < MG) ? wrow[(size_t)(t + 1) * MM + lane] : 0.f;
            e_n  = erow[(size_t)(t + 1) * DD + lane];
            a_n  = arow[(size_t)(t + 1) * DD + lane];
        }
        #pragma unroll
        for (int j = 0; j < MG; ++j) {
            const float wj = rdlane(wcur, j);
            const float f  = __builtin_fmaf(-wj, e_v, 1.f);
            A[j] *= f;
            B[j] = __builtin_fmaf(B[j], f, wj * a_v);
        }
    }

    if (wv == 0) {
        #pragma unroll
        for (int j = 0; j < MG; ++j)
            S[j][lane] = Mv0[(mb + j) * DD + lane];
    }
    __syncthreads();

    float Mv[MG];
    for (int w = 0; w < CHUNKS; ++w) {
        if (wv == w) {
            #pragma unroll
            for (int j = 0; j < MG; ++j) {
                Mv[j] = S[j][lane];
                S[j][lane] = __builtin_fmaf(A[j], Mv[j], B[j]);
            }
        }
        __syncthreads();
    }

    // entry state c = 2*wv  (t = 20*wv)
    float* st0 = states + ((size_t)(b * CR + 2 * wv) * MM + mb) * DD;
    #pragma unroll
    for (int j = 0; j < MG; ++j)
        st0[j * DD + lane] = Mv[j];

    // advance 10 dry steps -> entry state c = 2*wv+1
    wreg = (lane < MG) ? wrow[(size_t)t0 * MM + lane] : 0.f;
    e_n  = erow[(size_t)t0 * DD + lane];
    a_n  = arow[(size_t)t0 * DD + lane];
    for (int tt = 0; tt < CRL; ++tt) {
        const int t = t0 + tt;
        const float e_v = e_n, a_v = a_n, wcur = wreg;
        if (t + 1 < SEQ) {
            wreg = (lane < MG) ? wrow[(size_t)(t + 1) * MM + lane] : 0.f;
            e_n  = erow[(size_t)(t + 1) * DD + lane];
            a_n  = arow[(size_t)(t + 1) * DD + lane];
        }
        #pragma unroll
        for (int j = 0; j < MG; ++j) {
            const float wj = rdlane(wcur, j);
            Mv[j] = __builtin_fmaf(wj, __builtin_fmaf(-e_v, Mv[j], a_v), Mv[j]);
        }
    }
    float* st1 = states + ((size_t)(b * CR + 2 * wv + 1) * MM + mb) * DD;
    #pragma unroll
    for (int j = 0; j < MG; ++j)
        st1[j * DD + lane] = Mv[j];
}

// ---------------- K2r: replay with full-plane LDS staging + contiguous float4 slabs ----------------
// 2560 blocks (b,c) x 320 thr (5 m-waves). Per step: stage full 12.8KB plane in LDS
// (dbuf), 1 barrier, cooperative 800-float4 store -> each block writes a contiguous
// 128KB slab; consecutive blocks tile consecutive addresses (fill-shaped stream).
// Tail: in-block read reduce + f/p (K3 folded, proven round 12).
__global__ __launch_bounds__(320, 4) void k2r_replay(
    const int* __restrict__ q,
    const float* __restrict__ k_emb,
    const float* __restrict__ w_buf, const float* __restrict__ e_buf,
    const float* __restrict__ a_buf,
    const float* __restrict__ states,
    const float* __restrict__ Wf, const float* __restrict__ bfb,
    const float* __restrict__ Wp, const float* __restrict__ bp,
    float* __restrict__ out_p, float* __restrict__ out_Mv)
{
    __shared__ float splane[2][MM * DD];    // 2 x 12.8KB staging
    __shared__ float rpart[NMG][CRL][DD];   // 12.8KB read partials

    const int blk  = blockIdx.x;
    const int b    = blk / CR;
    const int c    = blk % CR;
    const int tid  = threadIdx.x;
    const int mg   = tid >> 6;      // 0..4
    const int lane = tid & 63;      // d
    const int t0   = c * CRL;
    const int mb   = mg * MG;

    const float* st = states + ((size_t)(b * CR + c) * MM + mb) * DD;
    float Mv[MG];
    #pragma unroll
    for (int j = 0; j < MG; ++j)
        Mv[j] = st[j * DD + lane];

    float* outb = out_Mv + (size_t)b * (SEQ + 1) * MM * DD;
    int p = 0;

    if (c == 0) {
        // plane 0 = Mv0 = entry state of chunk 0; stage + cooperative store
        #pragma unroll
        for (int j = 0; j < MG; ++j)
            splane[0][(mb + j) * DD + lane] = Mv[j];
        __syncthreads();
        #pragma unroll
        for (int k = 0; k < 3; ++k) {
            const int f = tid + 320 * k;
            if (f < MM * DD / 4) {
                const float4 v4 = *reinterpret_cast<const float4*>(&splane[0][4 * f]);
                *reinterpret_cast<float4*>(&outb[4 * f]) = v4;
            }
        }
        p = 1;
    }

    const float* wrow = w_buf + (size_t)b * SEQ * MM + mb;
    const float* erow = e_buf + (size_t)b * SEQ * DD;
    const float* arow = a_buf + (size_t)b * SEQ * DD;

    float wreg = (lane < MG) ? wrow[(size_t)t0 * MM + lane] : 0.f;
    float e_n  = erow[(size_t)t0 * DD + lane];
    float a_n  = arow[(size_t)t0 * DD + lane];

    for (int tt = 0; tt < CRL; ++tt) {
        const int t = t0 + tt;
        const float e_v = e_n, a_v = a_n, wcur = wreg;
        if (t + 1 < SEQ) {
            wreg = (lane < MG) ? wrow[(size_t)(t + 1) * MM + lane] : 0.f;
            e_n  = erow[(size_t)(t + 1) * DD + lane];
            a_n  = arow[(size_t)(t + 1) * DD + lane];
        }
        float racc0 = 0.f, racc1 = 0.f;
        #pragma unroll
        for (int j = 0; j < MG; ++j) {
            const float wj    = rdlane(wcur, j);
            const float m_old = Mv[j];
            if (j & 1) racc1 = __builtin_fmaf(wj, m_old, racc1);
            else       racc0 = __builtin_fmaf(wj, m_old, racc0);
            Mv[j] = __builtin_fmaf(wj, __builtin_fmaf(-e_v, m_old, a_v), m_old);
            splane[p][(mb + j) * DD + lane] = Mv[j];      // stage slice
        }
        rpart[mg][tt][lane] = racc0 + racc1;
        __syncthreads();   // plane staged by all 5 waves (also fences prior stores' LDS reads)

        float* outt = outb + (size_t)(t + 1) * MM * DD;
        #pragma unroll
        for (int k = 0; k < 3; ++k) {
            const int f = tid + 320 * k;
            if (f < MM * DD / 4) {
                const float4 v4 = *reinterpret_cast<const float4*>(&splane[p][4 * f]);
                *reinterpret_cast<float4*>(&outt[4 * f]) = v4;  // contiguous 12.8KB plane
            }
        }
        p ^= 1;
    }
    __syncthreads();

    // tail: f = tanh([read,k]@Wf+bf), p = sigmoid(f.Wp+bp); 2 t-rows per wave (proven r12)
    const float bf_l = bfb[lane];
    const float wp_l = Wp[lane];
    #pragma unroll
    for (int s = 0; s < 2; ++s) {
        const int tt = mg * 2 + s;
        const int t  = t0 + tt;
        float rsum = rpart[0][tt][lane];
        #pragma unroll
        for (int g = 1; g < NMG; ++g)
            rsum += rpart[g][tt][lane];

        int qi = q[b * SEQ + t];
        qi = min(max(qi, 0), NUMQ - 1);
        const float kreg = k_emb[(size_t)qi * DD + lane];

        float acc = bf_l;
        #pragma unroll
        for (int i = 0; i < DD; ++i)
            acc = __builtin_fmaf(__shfl(rsum, i, 64), Wf[i * DD + lane], acc);
        #pragma unroll
        for (int i = 0; i < DD; ++i)
            acc = __builtin_fmaf(__shfl(kreg, i, 64), Wf[(DD + i) * DD + lane], acc);
        const float f = tanhf(acc);

        float pv = f * wp_l;
        #pragma unroll
        for (int off = 32; off >= 1; off >>= 1)
            pv += __shfl_xor(pv, off, 64);
        if (lane == 0)
            out_p[(size_t)b * SEQ + t] = 1.f / (1.f + expf(-(pv + bp[0])));
    }
}

// ---------------- Last-resort fallback: round-5 fused single kernel (proven, ws-free) ----------------
__global__ __launch_bounds__(640) void dkvmn_fused(
    const int* q_, const int* r_,
    const float* k_emb, const float* v_emb, const float* Mk, const float* Mv0,
    const float* We, const float* be, const float* Wa, const float* ba,
    const float* Wf, const float* bfb, const float* Wp, const float* bp,
    float* out_p, float* out_Mv)
{
    __shared__ float Mk_l[MM][DD + 1];
    __shared__ bf16  ring[SEQ][DD];
    __shared__ int   q_row[SEQ], x_row[SEQ];
    __shared__ float kbuf[DD], vbuf[DD], vbuf2[DD];
    __shared__ float wst[MM], est[DD], ast[DD];
    __shared__ float partial[640];
    __shared__ float bias_e[DD], bias_a[DD];

    const int b    = blockIdx.x;
    const int tid  = threadIdx.x;
    const int wv   = tid >> 6;
    const int lane = tid & 63;

    for (int t = tid; t < SEQ; t += 640) {
        int qi = q_[b * SEQ + t], ri = r_[b * SEQ + t];
        qi = min(max(qi, 0), NUMQ - 1); ri = min(max(ri, 0), 1);
        q_row[t] = qi; x_row[t] = qi + ri * NUMQ;
    }
    for (int i = tid; i < MM * DD; i += 640) Mk_l[i >> 6][i & 63] = Mk[i];
    if (tid < DD) { bias_e[tid] = be[tid]; bias_a[tid] = ba[tid]; }

    const int d  = lane;
    const int m0 = wv * 5;
    float* outb = out_Mv + (size_t)b * (SEQ + 1) * MM * DD;
    float Mv[5];
    #pragma unroll
    for (int j = 0; j < 5; ++j) {
        Mv[j] = Mv0[(m0 + j) * DD + d];
        outb[(m0 + j) * DD + d] = Mv[j];
    }
    __syncthreads();

    float kf_n = 0.f, vf_n = 0.f, vf2_n = 0.f;
    if (wv == 0) kf_n  = k_emb[(size_t)q_row[0] * DD + lane];
    if (wv == 1) vf_n  = v_emb[(size_t)x_row[0] * DD + lane];
    if (wv == 2) vf2_n = v_emb[(size_t)x_row[0] * DD + lane];

    for (int t = 0; t < SEQ; ++t) {
        if (wv == 0) {
            kbuf[lane] = kf_n;
            if (t + 1 < SEQ) kf_n = k_emb[(size_t)q_row[t + 1] * DD + lane];
            float s = 0.f;
            if (lane < MM) {
                #pragma unroll
                for (int dd = 0; dd < DD; ++dd) s += kbuf[dd] * Mk_l[lane][dd];
            }
            float mx = (lane < MM) ? s : -1e30f;
            #pragma unroll
            for (int off = 32; off >= 1; off >>= 1) mx = fmaxf(mx, __shfl_xor(mx, off, 64));
            float ex = (lane < MM) ? expf(s - mx) : 0.f;
            float sm = ex;
            #pragma unroll
            for (int off = 32; off >= 1; off >>= 1) sm += __shfl_xor(sm, off, 64);
            if (lane < MM) wst[lane] = ex / sm;
        } else if (wv == 1) {
            vbuf[lane] = vf_n;
            if (t + 1 < SEQ) vf_n = v_emb[(size_t)x_row[t + 1] * DD + lane];
            float acc = bias_e[lane];
            #pragma unroll
            for (int dd = 0; dd < DD; ++dd) acc += vbuf[dd] * We[dd * DD + lane];
            est[lane] = 1.f / (1.f + expf(-acc));
        } else if (wv == 2) {
            vbuf2[lane] = vf2_n;
            if (t + 1 < SEQ) vf2_n = v_emb[(size_t)x_row[t + 1] * DD + lane];
            float acc = bias_a[lane];
            #pragma unroll
            for (int dd = 0; dd < DD; ++dd) acc += vbuf2[dd] * Wa[dd * DD + lane];
            ast[lane] = tanhf(acc);
        }
        __syncthreads();

        const float e_v = est[d];
        const float a_v = ast[d];
        float racc = 0.f;
        float* outt = outb + (size_t)(t + 1) * MM * DD;
        #pragma unroll
        for (int j = 0; j < 5; ++j) {
            const float wvv = wst[m0 + j];
            racc += wvv * Mv[j];
            Mv[j] = __builtin_fmaf(wvv, a_v - e_v * Mv[j], Mv[j]);
            outt[(m0 + j) * DD + d] = Mv[j];
        }
        partial[tid] = racc;
        __syncthreads();

        if (tid < DD) {
            float rr = 0.f;
            #pragma unroll
            for (int g = 0; g < 10; ++g) rr += partial[g * 64 + tid];
            ring[t][tid] = (bf16)rr;
        }
    }
    __syncthreads();

    for (int t = wv; t < SEQ; t += 10) {
        const int qi = q_row[t];
        const float kreg = k_emb[(size_t)qi * DD + lane];
        float acc = bfb[lane];
        #pragma unroll
        for (int i = 0; i < DD; ++i) acc += (float)ring[t][i] * Wf[i * DD + lane];
        #pragma unroll
        for (int i = 0; i < DD; ++i) acc += __shfl(kreg, i, 64) * Wf[(DD + i) * DD + lane];
        const float f = tanhf(acc);
        float pv = f * Wp[lane];
        #pragma unroll
        for (int off = 32; off >= 1; off >>= 1) pv += __shfl_xor(pv, off, 64);
        if (lane == 0)
            out_p[(size_t)b * SEQ + t] = 1.f / (1.f + expf(-(pv + bp[0])));
    }
}

extern "C" void kernel_launch(void* const* d_in, const int* in_sizes, int n_in,
                              void* d_out, int out_size, void* d_ws, size_t ws_size,
                              hipStream_t stream) {
    const int*   q     = (const int*)  d_in[0];
    const int*   r     = (const int*)  d_in[1];
    const float* k_emb = (const float*)d_in[4];
    const float* v_emb = (const float*)d_in[5];
    const float* Mk    = (const float*)d_in[6];
    const float* Mv0   = (const float*)d_in[7];
    const float* We    = (const float*)d_in[8];
    const float* be    = (const float*)d_in[9];
    const float* Wa    = (const float*)d_in[10];
    const float* ba    = (const float*)d_in[11];
    const float* Wf    = (const float*)d_in[12];
    const float* bfb   = (const float*)d_in[13];
    const float* Wp    = (const float*)d_in[14];
    const float* bp    = (const float*)d_in[15];

    float* out_p  = (float*)d_out;                 // [128,200]
    float* out_Mv = (float*)d_out + BATCH * SEQ;   // [128,201,50,64]

    const size_t N_W  = (size_t)BATCH * SEQ * MM;                 // w
    const size_t N_D  = (size_t)BATCH * SEQ * DD;                 // e / a
    const size_t N_ST = (size_t)BATCH * CR * MM * DD;             // states (32.8 MB)
    const size_t WS_NEEDED = (N_W + 2 * N_D + N_ST) * sizeof(float);  // ~51 MB

    const int rows = BATCH * SEQ;

    if (ws_size >= WS_NEEDED) {
        float* w_buf  = (float*)d_ws;          // [B,SEQ,50]
        float* e_buf  = w_buf + N_W;           // [B,SEQ,64]
        float* a_buf  = e_buf + N_D;           // [B,SEQ,64]
        float* states = a_buf + N_D;           // [B,CR,50,64]

        hipLaunchKernelGGL(k1_precompute, dim3(rows / 4), dim3(256), 0, stream,
                           q, r, k_emb, v_emb, Mk, We, be, Wa, ba, w_buf, e_buf, a_buf);
        hipLaunchKernelGGL(k2s_states, dim3(BATCH * NMG), dim3(640), 0, stream,
                           Mv0, w_buf, e_buf, a_buf, states);
        hipLaunchKernelGGL(k2r_replay, dim3(BATCH * CR), dim3(320), 0, stream,
                           q, k_emb, w_buf, e_buf, a_buf, states,
                           Wf, bfb, Wp, bp, out_p, out_Mv);
    } else {
        hipLaunchKernelGGL(dkvmn_fused, dim3(BATCH), dim3(640), 0, stream,
                           q, r, k_emb, v_emb, Mk, Mv0, We, be, Wa, ba,
                           Wf, bfb, Wp, bp, out_p, out_Mv);
    }
}

// Round 15
// 153.502 us; speedup vs baseline: 3.0076x; 3.0076x over previous
//
#include <hip/hip_runtime.h>
#include <hip/hip_bf16.h>

typedef __hip_bfloat16 bf16;

#define BATCH 128
#define SEQ   200
#define NUMQ  1000
#define DD    64
#define MM    50
#define MH    25     // m-half
#define CHUNKS 10
#define CLEN   20    // SEQ / CHUNKS
#define RPB   16     // rows per block in K1/K3

// Proven rounds 5-14: floats f32, ints int32, ws >= 31.3MB.
// PMC lessons: dword stores->RFO (r12); 2560-block replay->write amplification 2.5x
// (r14); k2_hier in-block scan is the best K2 (r13: 153.9us total).
// This round: K2 untouched; K1/K3 stage weights in LDS, 16 rows/block (16x less
// weight re-read traffic).

__device__ __forceinline__ float rdlane(float v, int j) {
    return __uint_as_float(__builtin_amdgcn_readlane(__float_as_uint(v), j));
}

// ---------------- K1': 16 rows/block, weights staged in LDS ----------------
__global__ __launch_bounds__(256) void k1_wide(
    const int* __restrict__ q, const int* __restrict__ r,
    const float* __restrict__ k_emb, const float* __restrict__ v_emb,
    const float* __restrict__ Mk,
    const float* __restrict__ We, const float* __restrict__ be,
    const float* __restrict__ Wa, const float* __restrict__ ba,
    float* __restrict__ w_buf, float* __restrict__ e_buf, float* __restrict__ a_buf)
{
    __shared__ float Mk_l[MM][DD + 1];   // 13.0 KB
    __shared__ float We_l[DD][DD + 1];   // 16.6 KB
    __shared__ float Wa_l[DD][DD + 1];   // 16.6 KB
    __shared__ float kv_l[4][128];       //  2.0 KB   total ~48.3 KB

    const int tid  = threadIdx.x;
    const int w    = tid >> 6;
    const int lane = tid & 63;

    for (int i = tid; i < MM * DD; i += 256) Mk_l[i >> 6][i & 63] = Mk[i];
    for (int i = tid; i < DD * DD; i += 256) {
        We_l[i >> 6][i & 63] = We[i];
        Wa_l[i >> 6][i & 63] = Wa[i];
    }
    __syncthreads();

    const float be_l = be[lane];
    const float ba_l = ba[lane];
    const int row0 = blockIdx.x * RPB;

    for (int it = 0; it < RPB / 4; ++it) {
        const int row = row0 + it * 4 + w;

        int qi = q[row], ri = r[row];
        qi = min(max(qi, 0), NUMQ - 1);
        ri = min(max(ri, 0), 1);
        const int xi = qi + ri * NUMQ;

        kv_l[w][lane]      = k_emb[(size_t)qi * DD + lane];   // same-wave write->read
        kv_l[w][64 + lane] = v_emb[(size_t)xi * DD + lane];

        // softmax over m (lane = m); Mk_l row-read is 2-way bank alias (free)
        float s = 0.f;
        if (lane < MM) {
            #pragma unroll
            for (int dd = 0; dd < DD; ++dd)
                s = __builtin_fmaf(kv_l[w][dd], Mk_l[lane][dd], s);
        }
        float mx = (lane < MM) ? s : -1e30f;
        #pragma unroll
        for (int off = 32; off >= 1; off >>= 1)
            mx = fmaxf(mx, __shfl_xor(mx, off, 64));
        float ex = (lane < MM) ? expf(s - mx) : 0.f;
        float sm = ex;
        #pragma unroll
        for (int off = 32; off >= 1; off >>= 1)
            sm += __shfl_xor(sm, off, 64);
        if (lane < MM)
            w_buf[(size_t)row * MM + lane] = ex / sm;

        // e, a (lane = d); weights from LDS (stride-65: conflict-free column reads)
        float ea = be_l, aa = ba_l;
        #pragma unroll
        for (int dd = 0; dd < DD; ++dd) {
            const float vb = kv_l[w][64 + dd];
            ea = __builtin_fmaf(vb, We_l[dd][lane], ea);
            aa = __builtin_fmaf(vb, Wa_l[dd][lane], aa);
        }
        e_buf[(size_t)row * DD + lane] = 1.f / (1.f + expf(-ea));
        a_buf[(size_t)row * DD + lane] = tanhf(aa);
    }
}

// ---------------- K2: r13 hierarchical in-block scan (verbatim, best measured) ----------------
__global__ __launch_bounds__(640) void k2_hier(
    const float* __restrict__ Mv0,
    const float* __restrict__ w_buf, const float* __restrict__ e_buf,
    const float* __restrict__ a_buf,
    float* __restrict__ read2_buf, float* __restrict__ out_Mv)
{
    __shared__ float POOL[CHUNKS * MH * DD];   // 64000 B

    const int blk  = blockIdx.x;
    const int b    = blk >> 1;
    const int h    = blk & 1;
    const int tid  = threadIdx.x;
    const int wv   = tid >> 6;
    const int lane = tid & 63;
    const int t0   = wv * CLEN;
    const int mb   = h * MH;

    const float* wrow = w_buf + (size_t)b * SEQ * MM + mb;
    const float* erow = e_buf + (size_t)b * SEQ * DD;
    const float* arow = a_buf + (size_t)b * SEQ * DD;

    float A[MH], B[MH];
    #pragma unroll
    for (int j = 0; j < MH; ++j) { A[j] = 1.f; B[j] = 0.f; }

    float wreg = (lane < MH) ? wrow[(size_t)t0 * MM + lane] : 0.f;
    float e_n  = erow[(size_t)t0 * DD + lane];
    float a_n  = arow[(size_t)t0 * DD + lane];

    for (int tt = 0; tt < CLEN; ++tt) {
        const int t = t0 + tt;
        const float e_v = e_n, a_v = a_n, wcur = wreg;
        if (t + 1 < SEQ) {
            wreg = (lane < MH) ? wrow[(size_t)(t + 1) * MM + lane] : 0.f;
            e_n  = erow[(size_t)(t + 1) * DD + lane];
            a_n  = arow[(size_t)(t + 1) * DD + lane];
        }
        #pragma unroll
        for (int j = 0; j < MH; ++j) {
            const float wj = rdlane(wcur, j);
            const float f  = __builtin_fmaf(-wj, e_v, 1.f);
            A[j] *= f;
            B[j] = __builtin_fmaf(B[j], f, wj * a_v);
        }
    }

    float* outb = out_Mv + (size_t)b * (SEQ + 1) * MM * DD + (size_t)mb * DD;
    if (wv == 0) {
        #pragma unroll
        for (int j = 0; j < MH; ++j) {
            const float m0v = Mv0[(mb + j) * DD + lane];
            POOL[j * DD + lane] = m0v;
            outb[j * DD + lane] = m0v;
        }
    }
    __syncthreads();

    float Mv[MH];
    for (int w = 0; w < CHUNKS; ++w) {
        if (wv == w) {
            #pragma unroll
            for (int j = 0; j < MH; ++j) {
                Mv[j] = POOL[j * DD + lane];
                POOL[j * DD + lane] = __builtin_fmaf(A[j], Mv[j], B[j]);
            }
        }
        __syncthreads();
    }

    float* rrow = read2_buf + ((size_t)h * BATCH + b) * SEQ * DD;
    float* sp   = POOL + wv * (MH * DD);

    wreg = (lane < MH) ? wrow[(size_t)t0 * MM + lane] : 0.f;
    e_n  = erow[(size_t)t0 * DD + lane];
    a_n  = arow[(size_t)t0 * DD + lane];

    for (int tt = 0; tt < CLEN; ++tt) {
        const int t = t0 + tt;
        const float e_v = e_n, a_v = a_n, wcur = wreg;
        if (t + 1 < SEQ) {
            wreg = (lane < MH) ? wrow[(size_t)(t + 1) * MM + lane] : 0.f;
            e_n  = erow[(size_t)(t + 1) * DD + lane];
            a_n  = arow[(size_t)(t + 1) * DD + lane];
        }
        float racc0 = 0.f, racc1 = 0.f;
        #pragma unroll
        for (int j = 0; j < MH; ++j) {
            const float wj    = rdlane(wcur, j);
            const float m_old = Mv[j];
            if (j & 1) racc1 = __builtin_fmaf(wj, m_old, racc1);
            else       racc0 = __builtin_fmaf(wj, m_old, racc0);
            Mv[j] = __builtin_fmaf(wj, __builtin_fmaf(-e_v, m_old, a_v), m_old);
            sp[j * DD + lane] = Mv[j];
        }
        float* outt = outb + (size_t)(t + 1) * MM * DD;
        #pragma unroll
        for (int k = 0; k < 7; ++k) {
            const int f = lane + 64 * k;
            if (f < MH * DD / 4) {
                const float4 v4 = *reinterpret_cast<const float4*>(&sp[4 * f]);
                *reinterpret_cast<float4*>(&outt[4 * f]) = v4;
            }
        }
        rrow[(size_t)t * DD + lane] = racc0 + racc1;
    }
}

// ---------------- K3': 16 rows/block, Wf staged in LDS ----------------
__global__ __launch_bounds__(256) void k3_wide(
    const int* __restrict__ q,
    const float* __restrict__ k_emb,
    const float* __restrict__ read2_buf,
    const float* __restrict__ Wf, const float* __restrict__ bfb,
    const float* __restrict__ Wp, const float* __restrict__ bp,
    float* __restrict__ out_p)
{
    __shared__ float Wf_l[2 * DD][DD + 1];   // 33.3 KB
    __shared__ float rk[4][128];             //  2.0 KB

    const int tid  = threadIdx.x;
    const int w    = tid >> 6;
    const int lane = tid & 63;

    for (int i = tid; i < 2 * DD * DD; i += 256)
        Wf_l[i >> 6][i & 63] = Wf[i];
    __syncthreads();

    const float bf_l = bfb[lane];
    const float wp_l = Wp[lane];
    const float bp0  = bp[0];
    const int row0 = blockIdx.x * RPB;

    const float* rd0 = read2_buf;
    const float* rd1 = read2_buf + (size_t)BATCH * SEQ * DD;

    for (int it = 0; it < RPB / 4; ++it) {
        const int row = row0 + it * 4 + w;

        int qi = q[row];
        qi = min(max(qi, 0), NUMQ - 1);
        rk[w][lane]      = rd0[(size_t)row * DD + lane] + rd1[(size_t)row * DD + lane];
        rk[w][64 + lane] = k_emb[(size_t)qi * DD + lane];   // same-wave write->read

        float acc = bf_l;
        #pragma unroll
        for (int i = 0; i < 2 * DD; ++i)
            acc = __builtin_fmaf(rk[w][i], Wf_l[i][lane], acc);
        const float f = tanhf(acc);

        float pv = f * wp_l;
        #pragma unroll
        for (int off = 32; off >= 1; off >>= 1)
            pv += __shfl_xor(pv, off, 64);
        if (lane == 0)
            out_p[row] = 1.f / (1.f + expf(-(pv + bp0)));
    }
}

// ---------------- Last-resort fallback: round-5 fused single kernel (proven, ws-free) ----------------
__global__ __launch_bounds__(640) void dkvmn_fused(
    const int* q_, const int* r_,
    const float* k_emb, const float* v_emb, const float* Mk, const float* Mv0,
    const float* We, const float* be, const float* Wa, const float* ba,
    const float* Wf, const float* bfb, const float* Wp, const float* bp,
    float* out_p, float* out_Mv)
{
    __shared__ float Mk_l[MM][DD + 1];
    __shared__ bf16  ring[SEQ][DD];
    __shared__ int   q_row[SEQ], x_row[SEQ];
    __shared__ float kbuf[DD], vbuf[DD], vbuf2[DD];
    __shared__ float wst[MM], est[DD], ast[DD];
    __shared__ float partial[640];
    __shared__ float bias_e[DD], bias_a[DD];

    const int b    = blockIdx.x;
    const int tid  = threadIdx.x;
    const int wv   = tid >> 6;
    const int lane = tid & 63;

    for (int t = tid; t < SEQ; t += 640) {
        int qi = q_[b * SEQ + t], ri = r_[b * SEQ + t];
        qi = min(max(qi, 0), NUMQ - 1); ri = min(max(ri, 0), 1);
        q_row[t] = qi; x_row[t] = qi + ri * NUMQ;
    }
    for (int i = tid; i < MM * DD; i += 640) Mk_l[i >> 6][i & 63] = Mk[i];
    if (tid < DD) { bias_e[tid] = be[tid]; bias_a[tid] = ba[tid]; }

    const int d  = lane;
    const int m0 = wv * 5;
    float* outb = out_Mv + (size_t)b * (SEQ + 1) * MM * DD;
    float Mv[5];
    #pragma unroll
    for (int j = 0; j < 5; ++j) {
        Mv[j] = Mv0[(m0 + j) * DD + d];
        outb[(m0 + j) * DD + d] = Mv[j];
    }
    __syncthreads();

    float kf_n = 0.f, vf_n = 0.f, vf2_n = 0.f;
    if (wv == 0) kf_n  = k_emb[(size_t)q_row[0] * DD + lane];
    if (wv == 1) vf_n  = v_emb[(size_t)x_row[0] * DD + lane];
    if (wv == 2) vf2_n = v_emb[(size_t)x_row[0] * DD + lane];

    for (int t = 0; t < SEQ; ++t) {
        if (wv == 0) {
            kbuf[lane] = kf_n;
            if (t + 1 < SEQ) kf_n = k_emb[(size_t)q_row[t + 1] * DD + lane];
            float s = 0.f;
            if (lane < MM) {
                #pragma unroll
                for (int dd = 0; dd < DD; ++dd) s += kbuf[dd] * Mk_l[lane][dd];
            }
            float mx = (lane < MM) ? s : -1e30f;
            #pragma unroll
            for (int off = 32; off >= 1; off >>= 1) mx = fmaxf(mx, __shfl_xor(mx, off, 64));
            float ex = (lane < MM) ? expf(s - mx) : 0.f;
            float sm = ex;
            #pragma unroll
            for (int off = 32; off >= 1; off >>= 1) sm += __shfl_xor(sm, off, 64);
            if (lane < MM) wst[lane] = ex / sm;
        } else if (wv == 1) {
            vbuf[lane] = vf_n;
            if (t + 1 < SEQ) vf_n = v_emb[(size_t)x_row[t + 1] * DD + lane];
            float acc = bias_e[lane];
            #pragma unroll
            for (int dd = 0; dd < DD; ++dd) acc += vbuf[dd] * We[dd * DD + lane];
            est[lane] = 1.f / (1.f + expf(-acc));
        } else if (wv == 2) {
            vbuf2[lane] = vf2_n;
            if (t + 1 < SEQ) vf2_n = v_emb[(size_t)x_row[t + 1] * DD + lane];
            float acc = bias_a[lane];
            #pragma unroll
            for (int dd = 0; dd < DD; ++dd) acc += vbuf2[dd] * Wa[dd * DD + lane];
            ast[lane] = tanhf(acc);
        }
        __syncthreads();

        const float e_v = est[d];
        const float a_v = ast[d];
        float racc = 0.f;
        float* outt = outb + (size_t)(t + 1) * MM * DD;
        #pragma unroll
        for (int j = 0; j < 5; ++j) {
            const float wvv = wst[m0 + j];
            racc += wvv * Mv[j];
            Mv[j] = __builtin_fmaf(wvv, a_v - e_v * Mv[j], Mv[j]);
            outt[(m0 + j) * DD + d] = Mv[j];
        }
        partial[tid] = racc;
        __syncthreads();

        if (tid < DD) {
            float rr = 0.f;
            #pragma unroll
            for (int g = 0; g < 10; ++g) rr += partial[g * 64 + tid];
            ring[t][tid] = (bf16)rr;
        }
    }
    __syncthreads();

    for (int t = wv; t < SEQ; t += 10) {
        const int qi = q_row[t];
        const float kreg = k_emb[(size_t)qi * DD + lane];
        float acc = bfb[lane];
        #pragma unroll
        for (int i = 0; i < DD; ++i) acc += (float)ring[t][i] * Wf[i * DD + lane];
        #pragma unroll
        for (int i = 0; i < DD; ++i) acc += __shfl(kreg, i, 64) * Wf[(DD + i) * DD + lane];
        const float f = tanhf(acc);
        float pv = f * Wp[lane];
        #pragma unroll
        for (int off = 32; off >= 1; off >>= 1) pv += __shfl_xor(pv, off, 64);
        if (lane == 0)
            out_p[(size_t)b * SEQ + t] = 1.f / (1.f + expf(-(pv + bp[0])));
    }
}

extern "C" void kernel_launch(void* const* d_in, const int* in_sizes, int n_in,
                              void* d_out, int out_size, void* d_ws, size_t ws_size,
                              hipStream_t stream) {
    const int*   q     = (const int*)  d_in[0];
    const int*   r     = (const int*)  d_in[1];
    const float* k_emb = (const float*)d_in[4];
    const float* v_emb = (const float*)d_in[5];
    const float* Mk    = (const float*)d_in[6];
    const float* Mv0   = (const float*)d_in[7];
    const float* We    = (const float*)d_in[8];
    const float* be    = (const float*)d_in[9];
    const float* Wa    = (const float*)d_in[10];
    const float* ba    = (const float*)d_in[11];
    const float* Wf    = (const float*)d_in[12];
    const float* bfb   = (const float*)d_in[13];
    const float* Wp    = (const float*)d_in[14];
    const float* bp    = (const float*)d_in[15];

    float* out_p  = (float*)d_out;                 // [128,200]
    float* out_Mv = (float*)d_out + BATCH * SEQ;   // [128,201,50,64]

    const size_t N_W  = (size_t)BATCH * SEQ * MM;      // w
    const size_t N_D  = (size_t)BATCH * SEQ * DD;      // e / a / read-half
    const size_t WS_NEEDED = (N_W + 4 * N_D) * sizeof(float);   // ~31.3 MB

    const int rows = BATCH * SEQ;

    if (ws_size >= WS_NEEDED) {
        float* w_buf     = (float*)d_ws;           // [B,SEQ,50]
        float* e_buf     = w_buf + N_W;            // [B,SEQ,64]
        float* a_buf     = e_buf + N_D;            // [B,SEQ,64]
        float* read2_buf = a_buf + N_D;            // [2,B,SEQ,64]

        hipLaunchKernelGGL(k1_wide, dim3(rows / RPB), dim3(256), 0, stream,
                           q, r, k_emb, v_emb, Mk, We, be, Wa, ba, w_buf, e_buf, a_buf);
        hipLaunchKernelGGL(k2_hier, dim3(BATCH * 2), dim3(640), 0, stream,
                           Mv0, w_buf, e_buf, a_buf, read2_buf, out_Mv);
        hipLaunchKernelGGL(k3_wide, dim3(rows / RPB), dim3(256), 0, stream,
                           q, k_emb, read2_buf, Wf, bfb, Wp, bp, out_p);
    } else {
        hipLaunchKernelGGL(dkvmn_fused, dim3(BATCH), dim3(640), 0, stream,
                           q, r, k_emb, v_emb, Mk, Mv0, We, be, Wa, ba,
                           Wf, bfb, Wp, bp, out_p, out_Mv);
    }
}